// Round 11
// baseline (166.900 us; speedup 1.0000x reference)
//
#include <hip/hip_runtime.h>
#include <math.h>

#define NB 8
#define TT 2048
#define DD 1024
#define NTI 16            // 2048 / 128 t-tiles
#define NPAIR 136         // NTI*(NTI+1)/2

typedef __attribute__((ext_vector_type(4))) int intx4;
typedef __attribute__((ext_vector_type(8))) int intx8;
typedef __attribute__((ext_vector_type(4))) float floatx4;

__device__ inline float fast_gelu(float x) {
    // tanh(z) = 1 - 2/(exp(2z)+1); __expf -> v_exp_f32
    float z = 0.7978845608028654f * (x + 0.044715f * x * x * x);
    float e = __expf(2.0f * z);
    float th = 1.0f - 2.0f / (e + 1.0f);
    return 0.5f * x * (1.0f + th);
}

// ------- kernel A: gelu + row norm + ema dot -> fp8 out_norm, ema_sim --------
// wave-per-row; ema normalization fused (L2-hot 4KB re-read per wave).
__global__ __launch_bounds__(256) void k_gelu_norm(
        const float* __restrict__ x, const float* __restrict__ ema,
        unsigned int* __restrict__ onrm8, float* __restrict__ ema_sim) {
    int row = blockIdx.x * 4 + (threadIdx.x >> 6);
    int lane = threadIdx.x & 63;
    const float4* xr = reinterpret_cast<const float4*>(x + (size_t)row * DD);
    const float4* er = reinterpret_cast<const float4*>(ema);
    float g[16];
    float ss = 0.f, dt = 0.f, e2 = 0.f;
#pragma unroll
    for (int j = 0; j < 4; ++j) {
        float4 v = xr[j * 64 + lane];
        float4 e = er[j * 64 + lane];
        float vv[4] = {v.x, v.y, v.z, v.w};
        float ee[4] = {e.x, e.y, e.z, e.w};
        e2 += ee[0] * ee[0] + ee[1] * ee[1] + ee[2] * ee[2] + ee[3] * ee[3];
#pragma unroll
        for (int i = 0; i < 4; ++i) {
            float o = fast_gelu(vv[i]);
            g[j * 4 + i] = o;
            ss += o * o;
            dt += o * ee[i];
        }
    }
#pragma unroll
    for (int m = 1; m < 64; m <<= 1) {
        ss += __shfl_xor(ss, m);
        dt += __shfl_xor(dt, m);
        e2 += __shfl_xor(e2, m);
    }
    float inv = 1.0f / fmaxf(sqrtf(ss), 1e-12f);
    float einv = 1.0f / fmaxf(sqrtf(e2), 1e-12f);
    unsigned int* o8 = onrm8 + (size_t)row * (DD / 4);
#pragma unroll
    for (int j = 0; j < 4; ++j) {
        int pk = 0;
        pk = __builtin_amdgcn_cvt_pk_fp8_f32(g[j * 4 + 0] * inv, g[j * 4 + 1] * inv, pk, false);
        pk = __builtin_amdgcn_cvt_pk_fp8_f32(g[j * 4 + 2] * inv, g[j * 4 + 3] * inv, pk, true);
        o8[j * 64 + lane] = (unsigned int)pk;
    }
    if (lane == 0) ema_sim[row] = dt * inv * einv;
}

// -------- kernel B: causal max similarity, 128x128 MX-fp8 MFMA GEMM ----------
// grid = NB*136 lower-tri 128x128 tile pairs, XCD-swizzled (batch per XCD;
// 2 MB fp8 slice L2-resident). 4 waves, each 64x64 = 4x4 frags of
// mfma_scale_f32_16x16x128_f8f6f4 (unit E8M0 scales = 127, fmt0 = e4m3 ->
// exact fp8 arithmetic, layout validated in R8). BK=128 -> 8 K-steps, half
// the barriers/staged bytes/LDS reads of the bf16 version. Single-buffer
// 32 KB LDS, global_load_lds w=16, XOR-pre-swizzled source (linear dest).
// __launch_bounds__(256,2): VGPR cap 256 -- fixes R8's spill storm (it had
// no bounds; compiler chose 64 VGPR and spilled 400 MB to scratch).
__global__ __launch_bounds__(256, 2) void k_seqmax(
        const unsigned char* __restrict__ onrm8, float* __restrict__ part) {
    __shared__ __align__(16) unsigned char lds[32768];   // A @0, B @16384

    int id = blockIdx.x;
    int nid = (id & 7) * NPAIR + (id >> 3);      // bijective: 1088 % 8 == 0
    int b = nid / NPAIR;
    int p = nid % NPAIR;
    int ti = (int)((sqrtf(8.0f * (float)p + 1.0f) - 1.0f) * 0.5f);
    while ((ti + 1) * (ti + 2) / 2 <= p) ++ti;
    while (ti * (ti + 1) / 2 > p) --ti;
    int sj = p - ti * (ti + 1) / 2;

    int lane = threadIdx.x & 63;
    int wave = threadIdx.x >> 6;
    int wr = wave >> 1, wc = wave & 1;
    int rl = lane & 15, g = lane >> 4;

    const unsigned char* Abase = onrm8 + (size_t)(b * TT + ti * 128) * DD;
    const unsigned char* Bbase = onrm8 + (size_t)(b * TT + sj * 128) * DD;

    floatx4 acc[4][4];
#pragma unroll
    for (int i = 0; i < 4; i++)
#pragma unroll
        for (int j = 0; j < 4; j++) acc[i][j] = (floatx4){0.f, 0.f, 0.f, 0.f};

    // stage 128x128 fp8 tile pair (16 KB each): 16 chunks of 1 KB per matrix,
    // 4 chunks per wave; 8 rows per chunk (128 B per row).
    auto stage = [&](int kt) {
#pragma unroll
        for (int i = 0; i < 4; ++i) {
            int c = wave * 4 + i;            // chunk 0..15
            int off = c * 1024 + lane * 16;  // linear LDS byte offset
            int row = off >> 7;              // 128 B per row
            int colb = (off & 127) ^ ((row & 7) << 4);
            const unsigned char* srcA = Abase + (size_t)row * DD + kt * 128 + colb;
            const unsigned char* srcB = Bbase + (size_t)row * DD + kt * 128 + colb;
            __builtin_amdgcn_global_load_lds(
                (const __attribute__((address_space(1))) unsigned int*)srcA,
                (__attribute__((address_space(3))) unsigned int*)(&lds[0] + c * 1024),
                16, 0, 0);
            __builtin_amdgcn_global_load_lds(
                (const __attribute__((address_space(1))) unsigned int*)srcB,
                (__attribute__((address_space(3))) unsigned int*)(&lds[16384] + c * 1024),
                16, 0, 0);
        }
    };

    // MX 16x16x128 fragment: lane (rl,g) holds k-bytes g*32..g*32+31 of row r
    // (layout validated by R8's passing run). Two b128 reads; conflict-free:
    // each consecutive-8-lane group covers all 8 XOR slots.
    int g2 = g * 2;
    auto ldfrag = [&](const unsigned char* base, int r) -> intx8 {
        int sw = (r & 7) << 4;
        intx4 lo = *(const intx4*)(base + r * 128 + ((g2 * 16) ^ sw));
        intx4 hi = *(const intx4*)(base + r * 128 + ((g2 * 16 + 16) ^ sw));
        return __builtin_shufflevector(lo, hi, 0, 1, 2, 3, 4, 5, 6, 7);
    };

    for (int kt = 0; kt < 8; ++kt) {
        stage(kt);
        __syncthreads();
        intx8 af[4], bg[4];
#pragma unroll
        for (int f = 0; f < 4; ++f) {
            af[f] = ldfrag(&lds[0], wr * 64 + f * 16 + rl);
            bg[f] = ldfrag(&lds[16384], wc * 64 + f * 16 + rl);
        }
#pragma unroll
        for (int fi = 0; fi < 4; ++fi)
#pragma unroll
            for (int fj = 0; fj < 4; ++fj)
                acc[fi][fj] = __builtin_amdgcn_mfma_scale_f32_16x16x128_f8f6f4(
                    af[fi], bg[fj], acc[fi][fj], 0, 0, 0, 127, 0, 127);
        __syncthreads();
    }

    // epilogue: strict-causal mask, row-max over this wave's 64-col half,
    // write partial to part[b][sj*2+wc][t]
    int t0g = ti * 128 + wr * 64;
    int s0g = sj * 128 + wc * 64;
#pragma unroll
    for (int fi = 0; fi < 4; ++fi) {
#pragma unroll
        for (int r = 0; r < 4; ++r) {
            int trow = t0g + fi * 16 + g * 4 + r;
            float m = -2.0f;
#pragma unroll
            for (int fj = 0; fj < 4; ++fj) {
                int scol = s0g + fj * 16 + rl;
                m = fmaxf(m, (scol < trow) ? acc[fi][fj][r] : -2.0f);
            }
#pragma unroll
            for (int msk = 1; msk < 16; msk <<= 1) m = fmaxf(m, __shfl_xor(m, msk));
            if (rl == 0)
                part[(((size_t)b * 32 + sj * 2 + wc) << 11) + trow] = m;
        }
    }
}

// ------- kernel C: reduce partials + gate + recompute gelu(x), wave-per-row --
__global__ __launch_bounds__(256) void k_gate(
        const float* __restrict__ x, float* __restrict__ out,
        const float* __restrict__ ema_sim, const float* __restrict__ part,
        const float* __restrict__ log_tau,
        const float* __restrict__ log_blend,
        const float* __restrict__ logit_blend_seq) {
    int row = blockIdx.x * 4 + (threadIdx.x >> 6);
    int lane = threadIdx.x & 63;
    int b = row >> 11;
    int t = row & (TT - 1);

    int n = 2 * ((t >> 7) + 1);              // 2..32 column-halves present
    float m = (lane < n) ? part[(((size_t)b * 32 + lane) << 11) + t] : -2.0f;
#pragma unroll
    for (int msk = 1; msk < 64; msk <<= 1) m = fmaxf(m, __shfl_xor(m, msk));

    float tau = __expf(log_tau[0]);
    float alpha = 1.f / (1.f + __expf(-log_blend[0]));
    float wseq = 1.f / (1.f + __expf(-logit_blend_seq[0]));
    float es = ema_sim[row];
    float sq = (t > 0) ? m : es;
    float fam = wseq * sq + (1.f - wseq) * es;
    float gate = 1.f - alpha + alpha * __expf(-tau * fam);

    const float4* xr = reinterpret_cast<const float4*>(x + (size_t)row * DD);
    float4* orow = reinterpret_cast<float4*>(out + (size_t)row * DD);
#pragma unroll
    for (int j = 0; j < 4; ++j) {
        float4 v = xr[j * 64 + lane];
        float4 o;
        o.x = fast_gelu(v.x) * gate;
        o.y = fast_gelu(v.y) * gate;
        o.z = fast_gelu(v.z) * gate;
        o.w = fast_gelu(v.w) * gate;
        orow[j * 64 + lane] = o;
    }
}

extern "C" void kernel_launch(void* const* d_in, const int* in_sizes, int n_in,
                              void* d_out, int out_size, void* d_ws, size_t ws_size,
                              hipStream_t stream) {
    const float* x = (const float*)d_in[0];
    const float* ema = (const float*)d_in[1];
    // d_in[2] = logit_decay (unused by reference)
    const float* log_tau = (const float*)d_in[3];
    const float* log_blend = (const float*)d_in[4];
    const float* logit_bs = (const float*)d_in[5];
    float* out = (float*)d_out;

    char* ws = (char*)d_ws;
    float* ema_sim = (float*)(ws + (4 << 10));            // 64 KB
    float* part = (float*)(ws + (132 << 10));             // 2 MB (8*32*2048 f32)
    unsigned char* onrm8 = (unsigned char*)(ws + ((size_t)2304 << 10));  // 16 MB fp8

    k_gelu_norm<<<NB * TT / 4, 256, 0, stream>>>(x, ema, (unsigned int*)onrm8, ema_sim);
    k_seqmax<<<NB * NPAIR, 256, 0, stream>>>(onrm8, part);
    k_gate<<<NB * TT / 4, 256, 0, stream>>>(x, out, ema_sim, part,
                                            log_tau, log_blend, logit_bs);
}

// Round 12
// 91.613 us; speedup vs baseline: 1.8218x; 1.8218x over previous
//
#include <hip/hip_runtime.h>
#include <math.h>

#define NB 8
#define TT 2048
#define DD 1024
#define NTI 16            // 2048 / 128 t-tiles
#define NPAIR 136         // NTI*(NTI+1)/2

typedef __attribute__((ext_vector_type(4))) float floatx4;
typedef __attribute__((ext_vector_type(2))) long longx2;

__device__ inline float fast_gelu(float x) {
    // tanh(z) = 1 - 2/(exp(2z)+1); __expf -> v_exp_f32
    float z = 0.7978845608028654f * (x + 0.044715f * x * x * x);
    float e = __expf(2.0f * z);
    float th = 1.0f - 2.0f / (e + 1.0f);
    return 0.5f * x * (1.0f + th);
}

// ------- kernel A: gelu + row norm + ema dot -> fp8 out_norm, ema_sim --------
// wave-per-row; ema normalization fused (L2-hot 4KB re-read per wave).
__global__ __launch_bounds__(256) void k_gelu_norm(
        const float* __restrict__ x, const float* __restrict__ ema,
        unsigned int* __restrict__ onrm8, float* __restrict__ ema_sim) {
    int row = blockIdx.x * 4 + (threadIdx.x >> 6);
    int lane = threadIdx.x & 63;
    const float4* xr = reinterpret_cast<const float4*>(x + (size_t)row * DD);
    const float4* er = reinterpret_cast<const float4*>(ema);
    float g[16];
    float ss = 0.f, dt = 0.f, e2 = 0.f;
#pragma unroll
    for (int j = 0; j < 4; ++j) {
        float4 v = xr[j * 64 + lane];
        float4 e = er[j * 64 + lane];
        float vv[4] = {v.x, v.y, v.z, v.w};
        float ee[4] = {e.x, e.y, e.z, e.w};
        e2 += ee[0] * ee[0] + ee[1] * ee[1] + ee[2] * ee[2] + ee[3] * ee[3];
#pragma unroll
        for (int i = 0; i < 4; ++i) {
            float o = fast_gelu(vv[i]);
            g[j * 4 + i] = o;
            ss += o * o;
            dt += o * ee[i];
        }
    }
#pragma unroll
    for (int m = 1; m < 64; m <<= 1) {
        ss += __shfl_xor(ss, m);
        dt += __shfl_xor(dt, m);
        e2 += __shfl_xor(e2, m);
    }
    float inv = 1.0f / fmaxf(sqrtf(ss), 1e-12f);
    float einv = 1.0f / fmaxf(sqrtf(e2), 1e-12f);
    unsigned int* o8 = onrm8 + (size_t)row * (DD / 4);
#pragma unroll
    for (int j = 0; j < 4; ++j) {
        int pk = 0;
        pk = __builtin_amdgcn_cvt_pk_fp8_f32(g[j * 4 + 0] * inv, g[j * 4 + 1] * inv, pk, false);
        pk = __builtin_amdgcn_cvt_pk_fp8_f32(g[j * 4 + 2] * inv, g[j * 4 + 3] * inv, pk, true);
        o8[j * 64 + lane] = (unsigned int)pk;
    }
    if (lane == 0) ema_sim[row] = dt * inv * einv;
}

// -------- kernel B: causal max similarity, 128x128 fp8 MFMA GEMM -------------
// grid = NB*136 lower-tri 128x128 tile pairs, XCD-swizzled (batch per XCD;
// 2 MB fp8 slice L2-resident). 4 waves, each 64x64 = 4x4 frags of
// mfma_f32_16x16x32_fp8_fp8. BK=128 fp8 -> 8 K-steps (half the staging and
// barriers of the bf16 version). Fragment loads are ds_read_b128 with the
// EXACT address pattern of the bf16 kernel (measured 0 bank conflicts):
// lane reads the 16B block (ks*32 + (g>>1)*16) ^ row-XOR and selects the
// 8B half with g&1 (v_cndmask pair, no LDS penalty). This replaces R9's
// ds_read_b64 pattern, which measured 4.46M conflict-cycles (~7 us/CU).
// Single-buffer 32 KB LDS, global_load_lds w=16, XOR-pre-swizzled source.
__global__ __launch_bounds__(256) void k_seqmax(const unsigned char* __restrict__ onrm8,
                                                float* __restrict__ part) {
    __shared__ __align__(16) unsigned char lds[32768];   // A @0, B @16384

    int id = blockIdx.x;
    int nid = (id & 7) * NPAIR + (id >> 3);      // bijective: 1088 % 8 == 0
    int b = nid / NPAIR;
    int p = nid % NPAIR;
    int ti = (int)((sqrtf(8.0f * (float)p + 1.0f) - 1.0f) * 0.5f);
    while ((ti + 1) * (ti + 2) / 2 <= p) ++ti;
    while (ti * (ti + 1) / 2 > p) --ti;
    int sj = p - ti * (ti + 1) / 2;

    int lane = threadIdx.x & 63;
    int wave = threadIdx.x >> 6;
    int wr = wave >> 1, wc = wave & 1;
    int rl = lane & 15, g = lane >> 4;
    int gh = g >> 1, gl = g & 1;

    const unsigned char* Abase = onrm8 + (size_t)(b * TT + ti * 128) * DD;
    const unsigned char* Bbase = onrm8 + (size_t)(b * TT + sj * 128) * DD;

    floatx4 acc[4][4];
#pragma unroll
    for (int i = 0; i < 4; i++)
#pragma unroll
        for (int j = 0; j < 4; j++) acc[i][j] = (floatx4){0.f, 0.f, 0.f, 0.f};

    // stage 128x128 fp8 tile pair (16 KB each): 16 chunks of 1 KB per matrix,
    // 4 chunks per wave; 8 rows per chunk (128 B per row).
    auto stage = [&](int kt) {
#pragma unroll
        for (int i = 0; i < 4; ++i) {
            int c = wave * 4 + i;            // chunk 0..15
            int off = c * 1024 + lane * 16;  // linear LDS byte offset
            int row = off >> 7;              // 128 B per row
            int colb = (off & 127) ^ ((row & 7) << 4);
            const unsigned char* srcA = Abase + (size_t)row * DD + kt * 128 + colb;
            const unsigned char* srcB = Bbase + (size_t)row * DD + kt * 128 + colb;
            __builtin_amdgcn_global_load_lds(
                (const __attribute__((address_space(1))) unsigned int*)srcA,
                (__attribute__((address_space(3))) unsigned int*)(&lds[0] + c * 1024),
                16, 0, 0);
            __builtin_amdgcn_global_load_lds(
                (const __attribute__((address_space(1))) unsigned int*)srcB,
                (__attribute__((address_space(3))) unsigned int*)(&lds[16384] + c * 1024),
                16, 0, 0);
        }
    };

    // fp8 16x16x32 fragment for slice ks: lane (rl,g) needs row r bytes
    // ks*32 + g*8 .. +8. Read the 16B block at ks*32 + gh*16 (same slot
    // pattern as the 0-conflict bf16 reads) and take half gl.
    auto ldfrag = [&](const unsigned char* base, int r, int ks) -> long {
        int sw = (r & 7) << 4;
        longx2 w = *(const longx2*)(base + r * 128 + ((ks * 32 + gh * 16) ^ sw));
        return gl ? w.y : w.x;
    };

    for (int kt = 0; kt < 8; ++kt) {
        stage(kt);
        __syncthreads();
#pragma unroll
        for (int ks = 0; ks < 4; ++ks) {
            long af[4], bg[4];
#pragma unroll
            for (int f = 0; f < 4; ++f) {
                af[f] = ldfrag(&lds[0], wr * 64 + f * 16 + rl, ks);
                bg[f] = ldfrag(&lds[16384], wc * 64 + f * 16 + rl, ks);
            }
#pragma unroll
            for (int fi = 0; fi < 4; ++fi)
#pragma unroll
                for (int fj = 0; fj < 4; ++fj)
                    acc[fi][fj] = __builtin_amdgcn_mfma_f32_16x16x32_fp8_fp8(
                        af[fi], bg[fj], acc[fi][fj], 0, 0, 0);
        }
        __syncthreads();
    }

    // epilogue: strict-causal mask, row-max over this wave's 64-col half,
    // write partial to part[b][sj*2+wc][t]
    int t0g = ti * 128 + wr * 64;
    int s0g = sj * 128 + wc * 64;
#pragma unroll
    for (int fi = 0; fi < 4; ++fi) {
#pragma unroll
        for (int r = 0; r < 4; ++r) {
            int trow = t0g + fi * 16 + g * 4 + r;
            float m = -2.0f;
#pragma unroll
            for (int fj = 0; fj < 4; ++fj) {
                int scol = s0g + fj * 16 + rl;
                m = fmaxf(m, (scol < trow) ? acc[fi][fj][r] : -2.0f);
            }
#pragma unroll
            for (int msk = 1; msk < 16; msk <<= 1) m = fmaxf(m, __shfl_xor(m, msk));
            if (rl == 0)
                part[(((size_t)b * 32 + sj * 2 + wc) << 11) + trow] = m;
        }
    }
}

// ------- kernel C: reduce partials + gate + recompute gelu(x), wave-per-row --
__global__ __launch_bounds__(256) void k_gate(
        const float* __restrict__ x, float* __restrict__ out,
        const float* __restrict__ ema_sim, const float* __restrict__ part,
        const float* __restrict__ log_tau,
        const float* __restrict__ log_blend,
        const float* __restrict__ logit_blend_seq) {
    int row = blockIdx.x * 4 + (threadIdx.x >> 6);
    int lane = threadIdx.x & 63;
    int b = row >> 11;
    int t = row & (TT - 1);

    int n = 2 * ((t >> 7) + 1);              // 2..32 column-halves present
    float m = (lane < n) ? part[(((size_t)b * 32 + lane) << 11) + t] : -2.0f;
#pragma unroll
    for (int msk = 1; msk < 64; msk <<= 1) m = fmaxf(m, __shfl_xor(m, msk));

    float tau = __expf(log_tau[0]);
    float alpha = 1.f / (1.f + __expf(-log_blend[0]));
    float wseq = 1.f / (1.f + __expf(-logit_blend_seq[0]));
    float es = ema_sim[row];
    float sq = (t > 0) ? m : es;
    float fam = wseq * sq + (1.f - wseq) * es;
    float gate = 1.f - alpha + alpha * __expf(-tau * fam);

    const float4* xr = reinterpret_cast<const float4*>(x + (size_t)row * DD);
    float4* orow = reinterpret_cast<float4*>(out + (size_t)row * DD);
#pragma unroll
    for (int j = 0; j < 4; ++j) {
        float4 v = xr[j * 64 + lane];
        float4 o;
        o.x = fast_gelu(v.x) * gate;
        o.y = fast_gelu(v.y) * gate;
        o.z = fast_gelu(v.z) * gate;
        o.w = fast_gelu(v.w) * gate;
        orow[j * 64 + lane] = o;
    }
}

extern "C" void kernel_launch(void* const* d_in, const int* in_sizes, int n_in,
                              void* d_out, int out_size, void* d_ws, size_t ws_size,
                              hipStream_t stream) {
    const float* x = (const float*)d_in[0];
    const float* ema = (const float*)d_in[1];
    // d_in[2] = logit_decay (unused by reference)
    const float* log_tau = (const float*)d_in[3];
    const float* log_blend = (const float*)d_in[4];
    const float* logit_bs = (const float*)d_in[5];
    float* out = (float*)d_out;

    char* ws = (char*)d_ws;
    float* ema_sim = (float*)(ws + (4 << 10));            // 64 KB
    float* part = (float*)(ws + (132 << 10));             // 2 MB (8*32*2048 f32)
    unsigned char* onrm8 = (unsigned char*)(ws + ((size_t)2304 << 10));  // 16 MB fp8

    k_gelu_norm<<<NB * TT / 4, 256, 0, stream>>>(x, ema, (unsigned int*)onrm8, ema_sim);
    k_seqmax<<<NB * NPAIR, 256, 0, stream>>>(onrm8, part);
    k_gate<<<NB * TT / 4, 256, 0, stream>>>(x, out, ema_sim, part,
                                            log_tau, log_blend, logit_bs);
}

// Round 13
// 73.321 us; speedup vs baseline: 2.2763x; 1.2495x over previous
//
#include <hip/hip_runtime.h>
#include <math.h>

#define NB 8
#define TT 2048
#define DD 1024
#define NTI 16            // 2048 / 128 t-tiles
#define NPAIR 136         // NTI*(NTI+1)/2

typedef __attribute__((ext_vector_type(4))) int intx4;
typedef __attribute__((ext_vector_type(4))) float floatx4;

__device__ inline float fast_gelu(float x) {
    // tanh(z) = 1 - 2/(exp(2z)+1); __expf -> v_exp_f32
    float z = 0.7978845608028654f * (x + 0.044715f * x * x * x);
    float e = __expf(2.0f * z);
    float th = 1.0f - 2.0f / (e + 1.0f);
    return 0.5f * x * (1.0f + th);
}

// ------- kernel A: gelu + row norm + ema dot -> int8 out_norm, ema_sim -------
// wave-per-row; ema normalization fused (L2-hot 4KB re-read per wave).
// int8 quant: |x_i * inv| <= 1 exactly, so round(127*x) is in [-127,127].
__global__ __launch_bounds__(256) void k_gelu_norm(
        const float* __restrict__ x, const float* __restrict__ ema,
        unsigned int* __restrict__ onrm8, float* __restrict__ ema_sim) {
    int row = blockIdx.x * 4 + (threadIdx.x >> 6);
    int lane = threadIdx.x & 63;
    const float4* xr = reinterpret_cast<const float4*>(x + (size_t)row * DD);
    const float4* er = reinterpret_cast<const float4*>(ema);
    float g[16];
    float ss = 0.f, dt = 0.f, e2 = 0.f;
#pragma unroll
    for (int j = 0; j < 4; ++j) {
        float4 v = xr[j * 64 + lane];
        float4 e = er[j * 64 + lane];
        float vv[4] = {v.x, v.y, v.z, v.w};
        float ee[4] = {e.x, e.y, e.z, e.w};
        e2 += ee[0] * ee[0] + ee[1] * ee[1] + ee[2] * ee[2] + ee[3] * ee[3];
#pragma unroll
        for (int i = 0; i < 4; ++i) {
            float o = fast_gelu(vv[i]);
            g[j * 4 + i] = o;
            ss += o * o;
            dt += o * ee[i];
        }
    }
#pragma unroll
    for (int m = 1; m < 64; m <<= 1) {
        ss += __shfl_xor(ss, m);
        dt += __shfl_xor(dt, m);
        e2 += __shfl_xor(e2, m);
    }
    float inv = 1.0f / fmaxf(sqrtf(ss), 1e-12f);
    float einv = 1.0f / fmaxf(sqrtf(e2), 1e-12f);
    unsigned int* o8 = onrm8 + (size_t)row * (DD / 4);
#pragma unroll
    for (int j = 0; j < 4; ++j) {
        int q0 = (int)rintf(g[j * 4 + 0] * inv * 127.0f);
        int q1 = (int)rintf(g[j * 4 + 1] * inv * 127.0f);
        int q2 = (int)rintf(g[j * 4 + 2] * inv * 127.0f);
        int q3 = (int)rintf(g[j * 4 + 3] * inv * 127.0f);
        unsigned pk = (q0 & 255) | ((q1 & 255) << 8) | ((q2 & 255) << 16) |
                      ((unsigned)(q3 & 255) << 24);
        o8[j * 64 + lane] = pk;
    }
    if (lane == 0) ema_sim[row] = dt * inv * einv;
}

// -------- kernel B: causal max similarity, 128x128 int8 MFMA GEMM ------------
// grid = NB*136 lower-tri 128x128 tile pairs, XCD-swizzled (batch per XCD;
// 2 MB i8 slice L2-resident). 4 waves, each 64x64 = 4x4 frags of
// mfma_i32_16x16x64_i8: lane (rl,g) holds 16 CONTIGUOUS k-bytes (v4i32) ->
// genuine ds_read_b128 at col (ks*64+g*16)^rowXOR, the exact slot pattern
// (ks*4+g)^v that the bf16 kernel measured at 0 bank conflicts. BK=128 i8 ->
// 8 K-steps: barriers, staged bytes, LDS reads all half the bf16 version,
// and i8 MFMA runs at 2x bf16 rate. Single-buffer 32 KB LDS, global_load_lds
// w=16, XOR-pre-swizzled source (linear LDS dest).
__global__ __launch_bounds__(256) void k_seqmax(const unsigned char* __restrict__ onrm8,
                                                float* __restrict__ part) {
    __shared__ __align__(16) unsigned char lds[32768];   // A @0, B @16384

    int id = blockIdx.x;
    int nid = (id & 7) * NPAIR + (id >> 3);      // bijective: 1088 % 8 == 0
    int b = nid / NPAIR;
    int p = nid % NPAIR;
    int ti = (int)((sqrtf(8.0f * (float)p + 1.0f) - 1.0f) * 0.5f);
    while ((ti + 1) * (ti + 2) / 2 <= p) ++ti;
    while (ti * (ti + 1) / 2 > p) --ti;
    int sj = p - ti * (ti + 1) / 2;

    int lane = threadIdx.x & 63;
    int wave = threadIdx.x >> 6;
    int wr = wave >> 1, wc = wave & 1;
    int rl = lane & 15, g = lane >> 4;

    const unsigned char* Abase = onrm8 + (size_t)(b * TT + ti * 128) * DD;
    const unsigned char* Bbase = onrm8 + (size_t)(b * TT + sj * 128) * DD;

    intx4 acc[4][4];
#pragma unroll
    for (int i = 0; i < 4; i++)
#pragma unroll
        for (int j = 0; j < 4; j++) acc[i][j] = (intx4){0, 0, 0, 0};

    // stage 128x128 i8 tile pair (16 KB each): 16 chunks of 1 KB per matrix,
    // 4 chunks per wave; 8 rows per chunk (128 B per row).
    auto stage = [&](int kt) {
#pragma unroll
        for (int i = 0; i < 4; ++i) {
            int c = wave * 4 + i;            // chunk 0..15
            int off = c * 1024 + lane * 16;  // linear LDS byte offset
            int row = off >> 7;              // 128 B per row
            int colb = (off & 127) ^ ((row & 7) << 4);
            const unsigned char* srcA = Abase + (size_t)row * DD + kt * 128 + colb;
            const unsigned char* srcB = Bbase + (size_t)row * DD + kt * 128 + colb;
            __builtin_amdgcn_global_load_lds(
                (const __attribute__((address_space(1))) unsigned int*)srcA,
                (__attribute__((address_space(3))) unsigned int*)(&lds[0] + c * 1024),
                16, 0, 0);
            __builtin_amdgcn_global_load_lds(
                (const __attribute__((address_space(1))) unsigned int*)srcB,
                (__attribute__((address_space(3))) unsigned int*)(&lds[16384] + c * 1024),
                16, 0, 0);
        }
    };

    // i8 16x16x64 fragment for slice ks: lane (rl,g) holds k-bytes
    // ks*64 + g*16 .. +15 of its row -- one aligned ds_read_b128.
    auto ldfrag = [&](const unsigned char* base, int r, int ks) -> intx4 {
        int sw = (r & 7) << 4;
        return *(const intx4*)(base + r * 128 + ((ks * 64 + g * 16) ^ sw));
    };

    for (int kt = 0; kt < 8; ++kt) {
        stage(kt);
        __syncthreads();
#pragma unroll
        for (int ks = 0; ks < 2; ++ks) {
            intx4 af[4], bg[4];
#pragma unroll
            for (int f = 0; f < 4; ++f) {
                af[f] = ldfrag(&lds[0], wr * 64 + f * 16 + rl, ks);
                bg[f] = ldfrag(&lds[16384], wc * 64 + f * 16 + rl, ks);
            }
#pragma unroll
            for (int fi = 0; fi < 4; ++fi)
#pragma unroll
                for (int fj = 0; fj < 4; ++fj)
                    acc[fi][fj] = __builtin_amdgcn_mfma_i32_16x16x64_i8(
                        af[fi], bg[fj], acc[fi][fj], 0, 0, 0);
        }
        __syncthreads();
    }

    // epilogue: strict-causal mask, row-max over this wave's 64-col half,
    // write partial to part[b][sj*2+wc][t]. sim = acc / 127^2.
    const float qs = 1.0f / 16129.0f;
    int t0g = ti * 128 + wr * 64;
    int s0g = sj * 128 + wc * 64;
#pragma unroll
    for (int fi = 0; fi < 4; ++fi) {
#pragma unroll
        for (int r = 0; r < 4; ++r) {
            int trow = t0g + fi * 16 + g * 4 + r;
            float m = -2.0f;
#pragma unroll
            for (int fj = 0; fj < 4; ++fj) {
                int scol = s0g + fj * 16 + rl;
                float v = (float)acc[fi][fj][r] * qs;
                m = fmaxf(m, (scol < trow) ? v : -2.0f);
            }
#pragma unroll
            for (int msk = 1; msk < 16; msk <<= 1) m = fmaxf(m, __shfl_xor(m, msk));
            if (rl == 0)
                part[(((size_t)b * 32 + sj * 2 + wc) << 11) + trow] = m;
        }
    }
}

// ------- kernel C: reduce partials + gate + recompute gelu(x), wave-per-row --
__global__ __launch_bounds__(256) void k_gate(
        const float* __restrict__ x, float* __restrict__ out,
        const float* __restrict__ ema_sim, const float* __restrict__ part,
        const float* __restrict__ log_tau,
        const float* __restrict__ log_blend,
        const float* __restrict__ logit_blend_seq) {
    int row = blockIdx.x * 4 + (threadIdx.x >> 6);
    int lane = threadIdx.x & 63;
    int b = row >> 11;
    int t = row & (TT - 1);

    int n = 2 * ((t >> 7) + 1);              // 2..32 column-halves present
    float m = (lane < n) ? part[(((size_t)b * 32 + lane) << 11) + t] : -2.0f;
#pragma unroll
    for (int msk = 1; msk < 64; msk <<= 1) m = fmaxf(m, __shfl_xor(m, msk));

    float tau = __expf(log_tau[0]);
    float alpha = 1.f / (1.f + __expf(-log_blend[0]));
    float wseq = 1.f / (1.f + __expf(-logit_blend_seq[0]));
    float es = ema_sim[row];
    float sq = (t > 0) ? m : es;
    float fam = wseq * sq + (1.f - wseq) * es;
    float gate = 1.f - alpha + alpha * __expf(-tau * fam);

    const float4* xr = reinterpret_cast<const float4*>(x + (size_t)row * DD);
    float4* orow = reinterpret_cast<float4*>(out + (size_t)row * DD);
#pragma unroll
    for (int j = 0; j < 4; ++j) {
        float4 v = xr[j * 64 + lane];
        float4 o;
        o.x = fast_gelu(v.x) * gate;
        o.y = fast_gelu(v.y) * gate;
        o.z = fast_gelu(v.z) * gate;
        o.w = fast_gelu(v.w) * gate;
        orow[j * 64 + lane] = o;
    }
}

extern "C" void kernel_launch(void* const* d_in, const int* in_sizes, int n_in,
                              void* d_out, int out_size, void* d_ws, size_t ws_size,
                              hipStream_t stream) {
    const float* x = (const float*)d_in[0];
    const float* ema = (const float*)d_in[1];
    // d_in[2] = logit_decay (unused by reference)
    const float* log_tau = (const float*)d_in[3];
    const float* log_blend = (const float*)d_in[4];
    const float* logit_bs = (const float*)d_in[5];
    float* out = (float*)d_out;

    char* ws = (char*)d_ws;
    float* ema_sim = (float*)(ws + (4 << 10));            // 64 KB
    float* part = (float*)(ws + (132 << 10));             // 2 MB (8*32*2048 f32)
    unsigned char* onrm8 = (unsigned char*)(ws + ((size_t)2304 << 10));  // 16 MB i8

    k_gelu_norm<<<NB * TT / 4, 256, 0, stream>>>(x, ema, (unsigned int*)onrm8, ema_sim);
    k_seqmax<<<NB * NPAIR, 256, 0, stream>>>(onrm8, part);
    k_gate<<<NB * TT / 4, 256, 0, stream>>>(x, out, ema_sim, part,
                                            log_tau, log_blend, logit_bs);
}

// Round 14
// 72.939 us; speedup vs baseline: 2.2882x; 1.0052x over previous
//
#include <hip/hip_runtime.h>
#include <math.h>

#define NB 8
#define TT 2048
#define DD 1024
#define NTI 16            // 2048 / 128 t-tiles
#define NPAIR 136         // NTI*(NTI+1)/2

typedef __attribute__((ext_vector_type(4))) int intx4;
typedef __attribute__((ext_vector_type(4))) float floatx4;

__device__ inline float fast_gelu(float x) {
    // tanh(z) = 1 - 2/(exp(2z)+1); __expf -> v_exp_f32
    float z = 0.7978845608028654f * (x + 0.044715f * x * x * x);
    float e = __expf(2.0f * z);
    float th = 1.0f - 2.0f / (e + 1.0f);
    return 0.5f * x * (1.0f + th);
}

// ------- kernel A: gelu + row norm + ema dot -> int8 out_norm, ema_sim -------
__global__ __launch_bounds__(256) void k_gelu_norm(
        const float* __restrict__ x, const float* __restrict__ ema,
        unsigned int* __restrict__ onrm8, float* __restrict__ ema_sim) {
    int row = blockIdx.x * 4 + (threadIdx.x >> 6);
    int lane = threadIdx.x & 63;
    const float4* xr = reinterpret_cast<const float4*>(x + (size_t)row * DD);
    const float4* er = reinterpret_cast<const float4*>(ema);
    float g[16];
    float ss = 0.f, dt = 0.f, e2 = 0.f;
#pragma unroll
    for (int j = 0; j < 4; ++j) {
        float4 v = xr[j * 64 + lane];
        float4 e = er[j * 64 + lane];
        float vv[4] = {v.x, v.y, v.z, v.w};
        float ee[4] = {e.x, e.y, e.z, e.w};
        e2 += ee[0] * ee[0] + ee[1] * ee[1] + ee[2] * ee[2] + ee[3] * ee[3];
#pragma unroll
        for (int i = 0; i < 4; ++i) {
            float o = fast_gelu(vv[i]);
            g[j * 4 + i] = o;
            ss += o * o;
            dt += o * ee[i];
        }
    }
#pragma unroll
    for (int m = 1; m < 64; m <<= 1) {
        ss += __shfl_xor(ss, m);
        dt += __shfl_xor(dt, m);
        e2 += __shfl_xor(e2, m);
    }
    float inv = 1.0f / fmaxf(sqrtf(ss), 1e-12f);
    float einv = 1.0f / fmaxf(sqrtf(e2), 1e-12f);
    unsigned int* o8 = onrm8 + (size_t)row * (DD / 4);
#pragma unroll
    for (int j = 0; j < 4; ++j) {
        int q0 = (int)rintf(g[j * 4 + 0] * inv * 127.0f);
        int q1 = (int)rintf(g[j * 4 + 1] * inv * 127.0f);
        int q2 = (int)rintf(g[j * 4 + 2] * inv * 127.0f);
        int q3 = (int)rintf(g[j * 4 + 3] * inv * 127.0f);
        unsigned pk = (q0 & 255) | ((q1 & 255) << 8) | ((q2 & 255) << 16) |
                      ((unsigned)(q3 & 255) << 24);
        o8[j * 64 + lane] = pk;
    }
    if (lane == 0) ema_sim[row] = dt * inv * einv;
}

// -------- kernel B: causal max similarity, 128x128 int8 MFMA GEMM ------------
// grid = NB*136 lower-tri 128x128 tile pairs, XCD-swizzled (batch per XCD).
// 4 waves, each 64x64 = 4x4 frags of mfma_i32_16x16x64_i8. BK=64 ->
// 16 K-steps, DOUBLE-buffered 2x16KB LDS with counted s_waitcnt vmcnt(4):
// issue stage(kt+1), wait only own stage(kt) loads, raw barrier (all waves'
// chunks of buf done), compute, raw barrier (reads done -> restage safe).
// No vmcnt(0) drain in the loop -- removes the m97-structural stall while
// keeping 4 blocks/CU (R5's version of this died at 64 KB LDS / 2 blocks).
// 64B rows use swizzle col ^= ((row>>1)&3)<<4: 16-lane groups cover each
// bank-quad exactly twice -> <=2-way (free). Stage source pre-swizzled with
// the SAME involution (linear LDS dest).
__global__ __launch_bounds__(256) void k_seqmax(const unsigned char* __restrict__ onrm8,
                                                float* __restrict__ part) {
    __shared__ __align__(16) unsigned char lds[2][16384];  // per buf: A@0, B@8192

    int id = blockIdx.x;
    int nid = (id & 7) * NPAIR + (id >> 3);      // bijective: 1088 % 8 == 0
    int b = nid / NPAIR;
    int p = nid % NPAIR;
    int ti = (int)((sqrtf(8.0f * (float)p + 1.0f) - 1.0f) * 0.5f);
    while ((ti + 1) * (ti + 2) / 2 <= p) ++ti;
    while (ti * (ti + 1) / 2 > p) --ti;
    int sj = p - ti * (ti + 1) / 2;

    int lane = threadIdx.x & 63;
    int wave = threadIdx.x >> 6;
    int wr = wave >> 1, wc = wave & 1;
    int rl = lane & 15, g = lane >> 4;

    const unsigned char* Abase = onrm8 + (size_t)(b * TT + ti * 128) * DD;
    const unsigned char* Bbase = onrm8 + (size_t)(b * TT + sj * 128) * DD;

    intx4 acc[4][4];
#pragma unroll
    for (int i = 0; i < 4; i++)
#pragma unroll
        for (int j = 0; j < 4; j++) acc[i][j] = (intx4){0, 0, 0, 0};

    // stage 128x64B i8 tile pair (8 KB each) into lds[buf]: 8 chunks of 1 KB
    // per matrix, 2 per wave per matrix -> 4 gload_lds per wave per stage.
    auto stage = [&](int buf, int kt) {
#pragma unroll
        for (int i = 0; i < 2; ++i) {
            int c = wave * 2 + i;            // chunk 0..7
            int off = c * 1024 + lane * 16;  // linear LDS byte offset
            int row = off >> 6;              // 64 B per row
            int colb = (off & 63) ^ (((row >> 1) & 3) << 4);
            const unsigned char* srcA = Abase + (size_t)row * DD + kt * 64 + colb;
            const unsigned char* srcB = Bbase + (size_t)row * DD + kt * 64 + colb;
            __builtin_amdgcn_global_load_lds(
                (const __attribute__((address_space(1))) unsigned int*)srcA,
                (__attribute__((address_space(3))) unsigned int*)(&lds[buf][0] + c * 1024),
                16, 0, 0);
            __builtin_amdgcn_global_load_lds(
                (const __attribute__((address_space(1))) unsigned int*)srcB,
                (__attribute__((address_space(3))) unsigned int*)(&lds[buf][8192] + c * 1024),
                16, 0, 0);
        }
    };

    // i8 16x16x64 fragment: lane (rl,g) holds the 16 k-bytes g*16..+15 of its
    // row -- one aligned ds_read_b128, swizzle-consistent with stage.
    auto ldfrag = [&](const unsigned char* base, int r) -> intx4 {
        return *(const intx4*)(base + r * 64 + ((g * 16) ^ (((r >> 1) & 3) << 4)));
    };

    stage(0, 0);
    for (int kt = 0; kt < 16; ++kt) {
        int buf = kt & 1;
        if (kt + 1 < 16) {
            stage(buf ^ 1, kt + 1);
            // own stage(kt) 4 loads retired (oldest); the 4 just issued fly on
            asm volatile("s_waitcnt vmcnt(4)" ::: "memory");
        } else {
            asm volatile("s_waitcnt vmcnt(0)" ::: "memory");
        }
        __builtin_amdgcn_s_barrier();            // all waves' stage(kt) done
        __builtin_amdgcn_sched_barrier(0);
        const unsigned char* Ab = &lds[buf][0];
        const unsigned char* Bb = &lds[buf][8192];
        intx4 af[4], bg[4];
#pragma unroll
        for (int f = 0; f < 4; ++f) {
            af[f] = ldfrag(Ab, wr * 64 + f * 16 + rl);
            bg[f] = ldfrag(Bb, wc * 64 + f * 16 + rl);
        }
        __builtin_amdgcn_s_setprio(1);
#pragma unroll
        for (int fi = 0; fi < 4; ++fi)
#pragma unroll
            for (int fj = 0; fj < 4; ++fj)
                acc[fi][fj] = __builtin_amdgcn_mfma_i32_16x16x64_i8(
                    af[fi], bg[fj], acc[fi][fj], 0, 0, 0);
        __builtin_amdgcn_s_setprio(0);
        __builtin_amdgcn_sched_barrier(0);
        __builtin_amdgcn_s_barrier();            // reads of buf done -> restage ok
    }

    // epilogue: strict-causal mask, row-max over this wave's 64-col half,
    // write partial to part[b][sj*2+wc][t]. sim = acc / 127^2.
    const float qs = 1.0f / 16129.0f;
    int t0g = ti * 128 + wr * 64;
    int s0g = sj * 128 + wc * 64;
#pragma unroll
    for (int fi = 0; fi < 4; ++fi) {
#pragma unroll
        for (int r = 0; r < 4; ++r) {
            int trow = t0g + fi * 16 + g * 4 + r;
            float m = -2.0f;
#pragma unroll
            for (int fj = 0; fj < 4; ++fj) {
                int scol = s0g + fj * 16 + rl;
                float v = (float)acc[fi][fj][r] * qs;
                m = fmaxf(m, (scol < trow) ? v : -2.0f);
            }
#pragma unroll
            for (int msk = 1; msk < 16; msk <<= 1) m = fmaxf(m, __shfl_xor(m, msk));
            if (rl == 0)
                part[(((size_t)b * 32 + sj * 2 + wc) << 11) + trow] = m;
        }
    }
}

// ------- kernel C: reduce partials + gate + recompute gelu(x), wave-per-row --
__global__ __launch_bounds__(256) void k_gate(
        const float* __restrict__ x, float* __restrict__ out,
        const float* __restrict__ ema_sim, const float* __restrict__ part,
        const float* __restrict__ log_tau,
        const float* __restrict__ log_blend,
        const float* __restrict__ logit_blend_seq) {
    int row = blockIdx.x * 4 + (threadIdx.x >> 6);
    int lane = threadIdx.x & 63;
    int b = row >> 11;
    int t = row & (TT - 1);

    int n = 2 * ((t >> 7) + 1);              // 2..32 column-halves present
    float m = (lane < n) ? part[(((size_t)b * 32 + lane) << 11) + t] : -2.0f;
#pragma unroll
    for (int msk = 1; msk < 64; msk <<= 1) m = fmaxf(m, __shfl_xor(m, msk));

    float tau = __expf(log_tau[0]);
    float alpha = 1.f / (1.f + __expf(-log_blend[0]));
    float wseq = 1.f / (1.f + __expf(-logit_blend_seq[0]));
    float es = ema_sim[row];
    float sq = (t > 0) ? m : es;
    float fam = wseq * sq + (1.f - wseq) * es;
    float gate = 1.f - alpha + alpha * __expf(-tau * fam);

    const float4* xr = reinterpret_cast<const float4*>(x + (size_t)row * DD);
    float4* orow = reinterpret_cast<float4*>(out + (size_t)row * DD);
#pragma unroll
    for (int j = 0; j < 4; ++j) {
        float4 v = xr[j * 64 + lane];
        float4 o;
        o.x = fast_gelu(v.x) * gate;
        o.y = fast_gelu(v.y) * gate;
        o.z = fast_gelu(v.z) * gate;
        o.w = fast_gelu(v.w) * gate;
        orow[j * 64 + lane] = o;
    }
}

extern "C" void kernel_launch(void* const* d_in, const int* in_sizes, int n_in,
                              void* d_out, int out_size, void* d_ws, size_t ws_size,
                              hipStream_t stream) {
    const float* x = (const float*)d_in[0];
    const float* ema = (const float*)d_in[1];
    // d_in[2] = logit_decay (unused by reference)
    const float* log_tau = (const float*)d_in[3];
    const float* log_blend = (const float*)d_in[4];
    const float* logit_bs = (const float*)d_in[5];
    float* out = (float*)d_out;

    char* ws = (char*)d_ws;
    float* ema_sim = (float*)(ws + (4 << 10));            // 64 KB
    float* part = (float*)(ws + (132 << 10));             // 2 MB (8*32*2048 f32)
    unsigned char* onrm8 = (unsigned char*)(ws + ((size_t)2304 << 10));  // 16 MB i8

    k_gelu_norm<<<NB * TT / 4, 256, 0, stream>>>(x, ema, (unsigned int*)onrm8, ema_sim);
    k_seqmax<<<NB * NPAIR, 256, 0, stream>>>(onrm8, part);
    k_gate<<<NB * TT / 4, 256, 0, stream>>>(x, out, ema_sim, part,
                                            log_tau, log_blend, logit_bs);
}